// Round 5
// baseline (229.416 us; speedup 1.0000x reference)
//
#include <hip/hip_runtime.h>
#include <math.h>

#define NCLS 80
#define BINS 16
#define BATCH 32
#define MAX_GT 32
#define NA 8400
#define AN (BATCH * NA)        // 268800 anchors total
#define NT 2100                // anchor-quads per batch image
#define NB_CLS 5120            // 2560 (b,c) planes x 2 blocks
#define NB_DFL 525             // 525*256*2 = 268800 dfl items
#define DFL_THREADS (NB_DFL * 256)
#define NSLOT 64
#define ALPHA_C 0.25f
#define W_CLS 1.0
#define W_IOU 7.5
#define W_DFL 1.5
#define EPS_F 1e-7f

// acc: 4 quantities x 64 slots of double: [0]=cls [1]=iou [2]=dfl [3]=pos_count

// block = 256 threads (4 waves). One atomic per call.
__device__ __forceinline__ void block_reduce_atomic(float val, double* __restrict__ target)
{
    __shared__ float s[4];
    __syncthreads();
    #pragma unroll
    for (int o = 32; o > 0; o >>= 1) val += __shfl_down(val, o);
    const int wave = threadIdx.x >> 6, lane = threadIdx.x & 63;
    if (lane == 0) s[wave] = val;
    __syncthreads();
    if (threadIdx.x == 0) atomicAdd(target, (double)(s[0] + s[1] + s[2] + s[3]));
}

// ---------------- prep: per-anchor label table (int8, -1 = negative) ----------------
__global__ __launch_bounds__(256) void yolo_prep(
    const int* __restrict__ matched, const int* __restrict__ gt_labels,
    signed char* __restrict__ lblmap)
{
    const int qid = blockIdx.x * 256 + threadIdx.x;    // anchor-quad id
    if (qid >= AN / 4) return;
    const int a0 = qid * 4;
    const int b  = a0 / NA;                            // quad never straddles b (8400%4==0)
    const int4 m4 = *(const int4*)(matched + a0);
    const int mm[4] = {m4.x, m4.y, m4.z, m4.w};
    char4 o;
    o.x = (mm[0] >= 0) ? (signed char)gt_labels[b * MAX_GT + mm[0]] : (signed char)-1;
    o.y = (mm[1] >= 0) ? (signed char)gt_labels[b * MAX_GT + mm[1]] : (signed char)-1;
    o.z = (mm[2] >= 0) ? (signed char)gt_labels[b * MAX_GT + mm[2]] : (signed char)-1;
    o.w = (mm[3] >= 0) ? (signed char)gt_labels[b * MAX_GT + mm[3]] : (signed char)-1;
    *(char4*)(lblmap + a0) = o;
}

// ---------------- mega: cls blocks (streaming) + dfl blocks (softmax) ----------------
__global__ __launch_bounds__(256) void yolo_mega(
    const float* __restrict__ p0, const float* __restrict__ p1, const float* __restrict__ p2,
    const float* __restrict__ gt_bboxes, const int* __restrict__ matched,
    const signed char* __restrict__ lblmap,
    float* __restrict__ pdist, double* __restrict__ acc)
{
    const int bid  = blockIdx.x;
    const int slot = bid & (NSLOT - 1);
    float part = 0.f;

    if (bid < NB_CLS) {
        // -------- classification: one (b,c) plane, half the anchors per block --------
        const int plane = bid >> 1;
        const int b = plane / NCLS;
        const int c = plane - b * NCLS;

        for (int t = (bid & 1) * 256 + (int)threadIdx.x; t < NT; t += 512) {
            const float* p; int HW, off, gbase;
            if (t < 1600)      { p = p0; HW = 6400; off = t * 4;          gbase = 0;    }
            else if (t < 2000) { p = p1; HW = 1600; off = (t - 1600) * 4; gbase = 6400; }
            else               { p = p2; HW = 400;  off = (t - 2000) * 4; gbase = 8000; }

            float4 q = *(const float4*)(p + (size_t)(b * 144 + 4 * BINS + c) * HW + off);
            char4 l4 = *(const char4*)(lblmap + b * NA + gbase + off);
            const int   lbl[4] = {l4.x, l4.y, l4.z, l4.w};
            const float s4[4]  = {q.x, q.y, q.z, q.w};
            #pragma unroll
            for (int j = 0; j < 4; ++j) {
                float s  = s4[j];
                float tt = (c == lbl[j]) ? 1.f : 0.f;
                float e   = __expf(-fabsf(s));
                float inv = 1.f / (1.f + e);
                float prob = (s >= 0.f) ? inv : e * inv;       // sigmoid
                float ce  = fmaxf(s, 0.f) - s * tt + __logf(1.f + e);
                float p_t = prob * tt + (1.f - prob) * (1.f - tt);
                float alpha_t = tt * ALPHA_C + (1.f - tt) * (1.f - ALPHA_C);
                float om = 1.f - p_t;
                part += alpha_t * om * om * ce;
            }
        }
        block_reduce_atomic(part, &acc[0 * NSLOT + slot]);
    } else {
        // -------- DFL: item = (k, b, anchor-quad); 2 items/thread --------
        const int dt0 = (bid - NB_CLS) * 256 + (int)threadIdx.x;
        #pragma unroll
        for (int rep = 0; rep < 2; ++rep) {
            const int it = dt0 + rep * DFL_THREADS;
            const int t  = it % NT;
            const int r  = it / NT;
            const int b  = r & 31;
            const int k  = r >> 5;

            const float* p; int HW, off, gbase, h, w0; float stride;
            if (t < 1600)      { p = p0; HW = 6400; off = t * 4;          gbase = 0;    stride = 8.f;
                                 h = t / 20;  w0 = (t - h * 20) * 4; }
            else if (t < 2000) { p = p1; HW = 1600; off = (t - 1600) * 4; gbase = 6400; stride = 16.f;
                                 int u = t - 1600; h = u / 10; w0 = (u - h * 10) * 4; }
            else               { p = p2; HW = 400;  off = (t - 2000) * 4; gbase = 8000; stride = 32.f;
                                 int u = t - 2000; h = u / 5;  w0 = (u - h * 5) * 4; }
            const float inv_s = 1.f / stride;
            const float cy = ((float)h + 0.5f) * stride;

            const int4 m4 = *(const int4*)(matched + (size_t)b * NA + gbase + off);
            const int mm[4] = {m4.x, m4.y, m4.z, m4.w};

            float tdv[4]; bool pos[4];
            #pragma unroll
            for (int j = 0; j < 4; ++j) {
                pos[j] = (mm[j] >= 0);
                int idx = pos[j] ? mm[j] : 0;
                float4 tb = *(const float4*)(gt_bboxes + ((size_t)b * MAX_GT + idx) * 4);
                float cx = ((float)(w0 + j) + 0.5f) * stride;
                float d = (k == 0) ? (cx - tb.x) : (k == 1) ? (cy - tb.y)
                        : (k == 2) ? (tb.z - cx) : (tb.w - cy);
                tdv[j] = fmaxf(d, 0.f) * inv_s;
            }

            const float* pc = p + (size_t)(b * 144 + k * BINS) * HW + off;
            float v[BINS][4];
            #pragma unroll
            for (int i = 0; i < BINS; ++i) {
                float4 q = *(const float4*)(pc + (size_t)i * HW);
                v[i][0] = q.x; v[i][1] = q.y; v[i][2] = q.z; v[i][3] = q.w;
            }

            float pd[4];
            #pragma unroll
            for (int j = 0; j < 4; ++j) {
                float tval = fminf(tdv[j], (float)(BINS - 1) - 1e-6f);
                int   lo = (int)floorf(tval);          // 0..14 -> lo+1 always valid
                float fr = tval - (float)lo;

                float mx = v[0][j];
                #pragma unroll
                for (int i = 1; i < BINS; ++i) mx = fmaxf(mx, v[i][j]);

                float se = 0.f, we = 0.f, vlo = 0.f, vhi = 0.f;
                #pragma unroll
                for (int i = 0; i < BINS; ++i) {
                    float e = __expf(v[i][j] - mx);
                    se += e;
                    we += (float)i * e;
                    vlo = (i == lo)     ? v[i][j] : vlo;
                    vhi = (i == lo + 1) ? v[i][j] : vhi;
                }
                pd[j] = (we / se) * stride;
                if (pos[j]) {
                    float lse = mx + __logf(se);
                    part += -((1.f - fr) * (vlo - lse) + fr * (vhi - lse));
                }
            }
            float4 st = {pd[0], pd[1], pd[2], pd[3]};
            *(float4*)(pdist + (size_t)k * AN + (size_t)b * NA + gbase + off) = st;
        }
        block_reduce_atomic(part, &acc[2 * NSLOT + slot]);
    }
}

// ---------------- IoU + positive count ----------------
__global__ __launch_bounds__(256) void yolo_iou(
    const float* __restrict__ gt_bboxes, const int* __restrict__ matched,
    const float* __restrict__ pdist, double* __restrict__ acc)
{
    const int t = blockIdx.x * 256 + threadIdx.x;
    const int b = blockIdx.y;
    const int slot = (blockIdx.x + blockIdx.y * 9) & (NSLOT - 1);

    float iou_acc = 0.f, cnt = 0.f;

    if (t < NT) {
        int HW, W, off, gbase; float stride;
        if (t < 1600)      { HW = 6400; W = 80; stride = 8.f;  off = t * 4;          gbase = 0;    }
        else if (t < 2000) { HW = 1600; W = 40; stride = 16.f; off = (t - 1600) * 4; gbase = 6400; }
        else               { HW = 400;  W = 20; stride = 32.f; off = (t - 2000) * 4; gbase = 8000; }

        const int h  = off / W;
        const int w0 = off - h * W;
        const float cy = ((float)h + 0.5f) * stride;

        const int4 m4 = *(const int4*)(matched + (size_t)b * NA + gbase + off);
        const int mm[4] = {m4.x, m4.y, m4.z, m4.w};

        float pdj[4][4];   // [k][j]
        #pragma unroll
        for (int k = 0; k < 4; ++k) {
            float4 q = *(const float4*)(pdist + (size_t)k * AN + (size_t)b * NA + gbase + off);
            pdj[k][0] = q.x; pdj[k][1] = q.y; pdj[k][2] = q.z; pdj[k][3] = q.w;
        }

        #pragma unroll
        for (int j = 0; j < 4; ++j) {
            if (mm[j] >= 0) {
                float4 tb = *(const float4*)(gt_bboxes + ((size_t)b * MAX_GT + mm[j]) * 4);
                float cx = ((float)(w0 + j) + 0.5f) * stride;
                float px1 = cx - pdj[0][j], py1 = cy - pdj[1][j];
                float px2 = cx + pdj[2][j], py2 = cy + pdj[3][j];
                float ix1 = fmaxf(px1, tb.x), iy1 = fmaxf(py1, tb.y);
                float ix2 = fminf(px2, tb.z), iy2 = fminf(py2, tb.w);
                float inter  = fmaxf(ix2 - ix1, 0.f) * fmaxf(iy2 - iy1, 0.f);
                float area_p = fmaxf(px2 - px1, 0.f) * fmaxf(py2 - py1, 0.f);
                float area_t = fmaxf(tb.z - tb.x, 0.f) * fmaxf(tb.w - tb.y, 0.f);
                float iou = inter / (area_p + area_t - inter + EPS_F);
                iou_acc += 1.f - iou;
                cnt += 1.f;
            }
        }
    }
    block_reduce_atomic(iou_acc, &acc[1 * NSLOT + slot]);
    block_reduce_atomic(cnt,     &acc[3 * NSLOT + slot]);
}

// ---------------- fallback: known-good fused kernel (round 1) ----------------
__global__ __launch_bounds__(256) void yolo_loss_fused(
    const float* __restrict__ p0, const float* __restrict__ p1, const float* __restrict__ p2,
    const float* __restrict__ gt_bboxes, const int* __restrict__ gt_labels,
    const int* __restrict__ matched, double* __restrict__ acc)
{
    const int a = blockIdx.x * blockDim.x + threadIdx.x;
    const int b = blockIdx.y;
    const int slot = blockIdx.x & (NSLOT - 1);
    float cls_acc = 0.f, iou_acc = 0.f, dfl_acc = 0.f, pos_cnt = 0.f;
    if (a < NA) {
        const float* p; int HW, W; float stride; int off;
        if (a < 6400)      { p = p0; HW = 6400; W = 80; stride = 8.f;  off = a; }
        else if (a < 8000) { p = p1; HW = 1600; W = 40; stride = 16.f; off = a - 6400; }
        else               { p = p2; HW = 400;  W = 20; stride = 32.f; off = a - 8000; }
        const int h = off / W, w = off - h * W;
        const float cx = ((float)w + 0.5f) * stride, cy = ((float)h + 0.5f) * stride;
        const float* pb = p + ((size_t)b * 144) * (size_t)HW + (size_t)off;
        const int m = matched[(size_t)b * NA + a];
        const bool pos = (m >= 0);
        const int idx = pos ? m : 0;
        const int lbl = gt_labels[b * MAX_GT + idx];
        const float* tbp = gt_bboxes + ((size_t)b * MAX_GT + idx) * 4;
        const float tx1 = tbp[0], ty1 = tbp[1], tx2 = tbp[2], ty2 = tbp[3];
        float tdist[4] = {fmaxf(cx - tx1, 0.f) / stride, fmaxf(cy - ty1, 0.f) / stride,
                          fmaxf(tx2 - cx, 0.f) / stride, fmaxf(ty2 - cy, 0.f) / stride};
        float pdv[4]; float dfl_sum = 0.f;
        #pragma unroll
        for (int k = 0; k < 4; ++k) {
            float tv = fminf(tdist[k], (float)(BINS - 1) - 1e-6f);
            int lo = (int)floorf(tv);
            float fr = tv - (float)lo;
            const float* pc = pb + (size_t)(k * BINS) * HW;
            float v[BINS];
            #pragma unroll
            for (int i = 0; i < BINS; ++i) v[i] = pc[(size_t)i * HW];
            float mx = v[0];
            #pragma unroll
            for (int i = 1; i < BINS; ++i) mx = fmaxf(mx, v[i]);
            float se = 0.f, we = 0.f, vlo = 0.f, vhi = 0.f;
            #pragma unroll
            for (int i = 0; i < BINS; ++i) {
                float e = __expf(v[i] - mx);
                se += e; we += (float)i * e;
                vlo = (i == lo) ? v[i] : vlo;
                vhi = (i == lo + 1) ? v[i] : vhi;
            }
            pdv[k] = (we / se) * stride;
            if (pos) { float lse = mx + __logf(se); dfl_sum += -((1.f - fr) * (vlo - lse) + fr * (vhi - lse)); }
        }
        const float* pcls = pb + (size_t)(4 * BINS) * HW;
        #pragma unroll 4
        for (int c = 0; c < NCLS; ++c) {
            float s = pcls[(size_t)c * HW];
            float tt = (pos && c == lbl) ? 1.f : 0.f;
            float e = __expf(-fabsf(s));
            float inv = 1.f / (1.f + e);
            float prob = (s >= 0.f) ? inv : e * inv;
            float ce = fmaxf(s, 0.f) - s * tt + __logf(1.f + e);
            float p_t = prob * tt + (1.f - prob) * (1.f - tt);
            float alpha_t = tt * ALPHA_C + (1.f - tt) * (1.f - ALPHA_C);
            float om = 1.f - p_t;
            cls_acc += alpha_t * om * om * ce;
        }
        if (pos) {
            float px1 = cx - pdv[0], py1 = cy - pdv[1], px2 = cx + pdv[2], py2 = cy + pdv[3];
            float ix1 = fmaxf(px1, tx1), iy1 = fmaxf(py1, ty1);
            float ix2 = fminf(px2, tx2), iy2 = fminf(py2, ty2);
            float inter  = fmaxf(ix2 - ix1, 0.f) * fmaxf(iy2 - iy1, 0.f);
            float area_p = fmaxf(px2 - px1, 0.f) * fmaxf(py2 - py1, 0.f);
            float area_t = fmaxf(tx2 - tx1, 0.f) * fmaxf(ty2 - ty1, 0.f);
            float iou = inter / (area_p + area_t - inter + EPS_F);
            iou_acc = 1.f - iou; dfl_acc = dfl_sum; pos_cnt = 1.f;
        }
    }
    block_reduce_atomic(cls_acc, &acc[0 * NSLOT + slot]);
    block_reduce_atomic(iou_acc, &acc[1 * NSLOT + slot]);
    block_reduce_atomic(dfl_acc, &acc[2 * NSLOT + slot]);
    block_reduce_atomic(pos_cnt, &acc[3 * NSLOT + slot]);
}

__global__ void yolo_loss_finalize(const double* __restrict__ acc, float* __restrict__ out)
{
    double s[4] = {0.0, 0.0, 0.0, 0.0};
    for (int q = 0; q < 4; ++q)
        for (int i = 0; i < NSLOT; ++i) s[q] += acc[q * NSLOT + i];
    double np = s[3] < 1.0 ? 1.0 : s[3];
    double total = W_CLS * s[0] / np + W_IOU * s[1] / np + W_DFL * s[2] / (np * 4.0);
    out[0] = (float)total;
}

extern "C" void kernel_launch(void* const* d_in, const int* in_sizes, int n_in,
                              void* d_out, int out_size, void* d_ws, size_t ws_size,
                              hipStream_t stream)
{
    const float* p0        = (const float*)d_in[0];
    const float* p1        = (const float*)d_in[1];
    const float* p2        = (const float*)d_in[2];
    const float* gt_bboxes = (const float*)d_in[3];
    const int*   gt_labels = (const int*)d_in[4];
    const int*   matched   = (const int*)d_in[5];
    float*  out = (float*)d_out;

    const size_t accBytes   = 4 * NSLOT * sizeof(double);               // 2048
    const size_t pdistBytes = (size_t)4 * AN * sizeof(float);           // 4,300,800
    double*      acc    = (double*)d_ws;
    float*       pdist  = (float*)((char*)d_ws + accBytes);
    signed char* lblmap = (signed char*)((char*)d_ws + accBytes + pdistBytes);
    const size_t need = accBytes + pdistBytes + (size_t)AN;             // ~4.57 MB

    (void)hipMemsetAsync(acc, 0, accBytes, stream);

    if (ws_size >= need) {
        yolo_prep<<<(AN / 4 + 255) / 256, 256, 0, stream>>>(matched, gt_labels, lblmap);
        yolo_mega<<<NB_CLS + NB_DFL, 256, 0, stream>>>(p0, p1, p2, gt_bboxes, matched,
                                                       lblmap, pdist, acc);
        dim3 g2((NT + 255) / 256, BATCH);
        yolo_iou<<<g2, 256, 0, stream>>>(gt_bboxes, matched, pdist, acc);
    } else {
        dim3 g((NA + 255) / 256, BATCH);
        yolo_loss_fused<<<g, 256, 0, stream>>>(p0, p1, p2, gt_bboxes, gt_labels, matched, acc);
    }
    yolo_loss_finalize<<<1, 1, 0, stream>>>(acc, out);
}

// Round 6
// 213.503 us; speedup vs baseline: 1.0745x; 1.0745x over previous
//
#include <hip/hip_runtime.h>
#include <math.h>

#define NCLS 80
#define BINS 16
#define BATCH 32
#define MAX_GT 32
#define NA 8400
#define AN (BATCH * NA)        // 268800 anchors total
#define NT 2100                // anchor-quads per image
#define NB_DFL 1050            // 1050*256 = 268800 = (2100 quads * 4 sides * 32 b)
#define NB_CLS 2560            // one block per (b, c) plane
#define NSLOT 64
#define ALPHA_C 0.25f
#define W_CLS 1.0
#define W_IOU 7.5
#define W_DFL 1.5
#define EPS_F 1e-7f

// acc: 4 quantities x 64 slots (double): [0]=cls [1]=iou [2]=dfl [3]=pos_count

__device__ __forceinline__ void block_reduce_atomic(float val, double* __restrict__ target)
{
    __shared__ float s[4];
    __syncthreads();
    #pragma unroll
    for (int o = 32; o > 0; o >>= 1) val += __shfl_down(val, o);
    const int wave = threadIdx.x >> 6, lane = threadIdx.x & 63;
    if (lane == 0) s[wave] = val;
    __syncthreads();
    if (threadIdx.x == 0) atomicAdd(target, (double)(s[0] + s[1] + s[2] + s[3]));
}

__device__ __forceinline__ float focal_elem(float s, float tt)
{
    float e   = __expf(-fabsf(s));
    float inv = 1.f / (1.f + e);
    float prob = (s >= 0.f) ? inv : e * inv;           // sigmoid(s)
    float ce  = fmaxf(s, 0.f) - s * tt + __logf(1.f + e);
    float p_t = prob * tt + (1.f - prob) * (1.f - tt);
    float alpha_t = tt * ALPHA_C + (1.f - tt) * (1.f - ALPHA_C);
    float om = 1.f - p_t;
    return alpha_t * om * om * ce;
}

// ---------------- prep: per-anchor int8 label table (-1 = negative) + zero acc ----------------
__global__ __launch_bounds__(256) void yolo_prep(
    const int* __restrict__ matched, const int* __restrict__ gt_labels,
    signed char* __restrict__ lblmap, double* __restrict__ acc)
{
    if (blockIdx.x == 0) acc[threadIdx.x] = 0.0;       // 256 = 4*NSLOT doubles
    const int qid = blockIdx.x * 256 + threadIdx.x;
    if (qid >= AN / 4) return;
    const int a0 = qid * 4;
    const int b  = a0 / NA;                            // quad never straddles b
    const int4 m4 = *(const int4*)(matched + a0);
    const int mm[4] = {m4.x, m4.y, m4.z, m4.w};
    char4 o;
    o.x = (mm[0] >= 0) ? (signed char)gt_labels[b * MAX_GT + mm[0]] : (signed char)-1;
    o.y = (mm[1] >= 0) ? (signed char)gt_labels[b * MAX_GT + mm[1]] : (signed char)-1;
    o.z = (mm[2] >= 0) ? (signed char)gt_labels[b * MAX_GT + mm[2]] : (signed char)-1;
    o.w = (mm[3] >= 0) ? (signed char)gt_labels[b * MAX_GT + mm[3]] : (signed char)-1;
    *(char4*)(lblmap + a0) = o;
}

// ---------------- mega: DFL+IoU blocks first, then cls plane blocks ----------------
__global__ __launch_bounds__(256) void yolo_mega(
    const float* __restrict__ p0, const float* __restrict__ p1, const float* __restrict__ p2,
    const float* __restrict__ gt_bboxes, const int* __restrict__ matched,
    const signed char* __restrict__ lblmap, double* __restrict__ acc)
{
    const int bid  = blockIdx.x;
    const int slot = bid & (NSLOT - 1);

    if (bid < NB_DFL) {
        // ---- DFL + IoU: thread = (anchor-quad, side k); 4 threads/quad share via LDS ----
        __shared__ float spd[64][4][4];                // [quad-group][k][j]
        const int gdt = bid * 256 + (int)threadIdx.x;  // 0..268799
        const int k   = gdt & 3;
        const int qg  = gdt >> 2;                      // 0..67199
        const int b   = qg / NT;
        const int t   = qg - b * NT;

        const float* p; int HW, off, gbase, h, w0; float stride;
        if (t < 1600)      { p = p0; HW = 6400; off = t * 4;          gbase = 0;    stride = 8.f;
                             h = t / 20;  w0 = (t - h * 20) * 4; }
        else if (t < 2000) { p = p1; HW = 1600; off = (t - 1600) * 4; gbase = 6400; stride = 16.f;
                             int u = t - 1600; h = u / 10; w0 = (u - h * 10) * 4; }
        else               { p = p2; HW = 400;  off = (t - 2000) * 4; gbase = 8000; stride = 32.f;
                             int u = t - 2000; h = u / 5;  w0 = (u - h * 5) * 4; }
        const float inv_s = 1.f / stride;
        const float cy = ((float)h + 0.5f) * stride;

        // ---- issue all global loads up front (16 bin-rows + matched + 4 box gathers) ----
        const float* pc = p + (size_t)(b * 144 + k * BINS) * HW + off;
        float v[BINS][4];
        #pragma unroll
        for (int i = 0; i < BINS; ++i) {
            float4 q = *(const float4*)(pc + (size_t)i * HW);
            v[i][0] = q.x; v[i][1] = q.y; v[i][2] = q.z; v[i][3] = q.w;
        }
        const int4 m4 = *(const int4*)(matched + (size_t)b * NA + gbase + off);
        const int mm[4] = {m4.x, m4.y, m4.z, m4.w};
        bool pos[4]; float4 tbv[4]; float tdv[4];
        #pragma unroll
        for (int j = 0; j < 4; ++j) {
            pos[j] = (mm[j] >= 0);
            int idx = pos[j] ? mm[j] : 0;
            tbv[j] = *(const float4*)(gt_bboxes + ((size_t)b * MAX_GT + idx) * 4);
            float cx = ((float)(w0 + j) + 0.5f) * stride;
            float d = (k == 0) ? (cx - tbv[j].x) : (k == 1) ? (cy - tbv[j].y)
                    : (k == 2) ? (tbv[j].z - cx) : (tbv[j].w - cy);
            tdv[j] = fmaxf(d, 0.f) * inv_s;
        }

        float part = 0.f;
        float pd[4];
        #pragma unroll
        for (int j = 0; j < 4; ++j) {
            float tval = fminf(tdv[j], (float)(BINS - 1) - 1e-6f);
            int   lo = (int)floorf(tval);              // 0..14 -> lo+1 valid
            float fr = tval - (float)lo;
            float mx = v[0][j];
            #pragma unroll
            for (int i = 1; i < BINS; ++i) mx = fmaxf(mx, v[i][j]);
            float se = 0.f, we = 0.f, vlo = 0.f, vhi = 0.f;
            #pragma unroll
            for (int i = 0; i < BINS; ++i) {
                float e = __expf(v[i][j] - mx);
                se += e;
                we += (float)i * e;
                vlo = (i == lo)     ? v[i][j] : vlo;
                vhi = (i == lo + 1) ? v[i][j] : vhi;
            }
            pd[j] = (we / se) * stride;
            if (pos[j]) {
                float lse = mx + __logf(se);
                part += -((1.f - fr) * (vlo - lse) + fr * (vhi - lse));
            }
        }
        *(float4*)&spd[threadIdx.x >> 2][k][0] = make_float4(pd[0], pd[1], pd[2], pd[3]);
        __syncthreads();

        float iou_part = 0.f, cnt = 0.f;
        if (k == 0) {
            const int g = threadIdx.x >> 2;
            #pragma unroll
            for (int j = 0; j < 4; ++j) {
                if (pos[j]) {
                    float cx = ((float)(w0 + j) + 0.5f) * stride;
                    float px1 = cx - spd[g][0][j], py1 = cy - spd[g][1][j];
                    float px2 = cx + spd[g][2][j], py2 = cy + spd[g][3][j];
                    float4 tb = tbv[j];
                    float ix1 = fmaxf(px1, tb.x), iy1 = fmaxf(py1, tb.y);
                    float ix2 = fminf(px2, tb.z), iy2 = fminf(py2, tb.w);
                    float inter  = fmaxf(ix2 - ix1, 0.f) * fmaxf(iy2 - iy1, 0.f);
                    float area_p = fmaxf(px2 - px1, 0.f) * fmaxf(py2 - py1, 0.f);
                    float area_t = fmaxf(tb.z - tb.x, 0.f) * fmaxf(tb.w - tb.y, 0.f);
                    float iou = inter / (area_p + area_t - inter + EPS_F);
                    iou_part += 1.f - iou;
                    cnt += 1.f;
                }
            }
        }
        block_reduce_atomic(part,     &acc[2 * NSLOT + slot]);
        block_reduce_atomic(iou_part, &acc[1 * NSLOT + slot]);
        block_reduce_atomic(cnt,      &acc[3 * NSLOT + slot]);
    } else {
        // ---- cls: one (b,c) plane per block; 9 chunks, ALL loads issued up front ----
        const int cbid = bid - NB_DFL;                 // 0..2559
        const int b = cbid / NCLS;
        const int c = cbid - b * NCLS;
        const size_t cls_ch = (size_t)(b * 144 + 4 * BINS + c);
        const signed char* lb0 = lblmap + b * NA;

        float4 q[9];
        char4  l4[9];
        const float* pl0 = p0 + cls_ch * 6400;
        #pragma unroll
        for (int i = 0; i < 6; ++i) {                  // chunks 0..5: pure p0 (t <= 1535)
            int off = (i * 256 + (int)threadIdx.x) * 4;
            q[i]  = *(const float4*)(pl0 + off);
            l4[i] = *(const char4*)(lb0 + off);
        }
        #pragma unroll
        for (int i = 6; i < 9; ++i) {                  // chunks 6..8: mixed scales
            int t  = i * 256 + (int)threadIdx.x;
            int tc = (t < NT) ? t : 0;
            const float* p; int HW, off, gbase;
            if (tc < 1600)      { p = p0; HW = 6400; off = tc * 4;          gbase = 0;    }
            else if (tc < 2000) { p = p1; HW = 1600; off = (tc - 1600) * 4; gbase = 6400; }
            else                { p = p2; HW = 400;  off = (tc - 2000) * 4; gbase = 8000; }
            q[i]  = *(const float4*)(p + cls_ch * HW + off);
            l4[i] = *(const char4*)(lb0 + gbase + off);
        }

        float part = 0.f;
        #pragma unroll
        for (int i = 0; i < 9; ++i) {
            const bool valid = (i < 8) || (i * 256 + (int)threadIdx.x < NT);
            const float s4[4]  = {q[i].x, q[i].y, q[i].z, q[i].w};
            const int   lbl[4] = {l4[i].x, l4[i].y, l4[i].z, l4[i].w};
            float sum = 0.f;
            #pragma unroll
            for (int j = 0; j < 4; ++j)
                sum += focal_elem(s4[j], (c == lbl[j]) ? 1.f : 0.f);
            part += valid ? sum : 0.f;
        }
        block_reduce_atomic(part, &acc[0 * NSLOT + slot]);
    }
}

// ---------------- fallback: known-good fused kernel (round 1) ----------------
__global__ __launch_bounds__(256) void yolo_loss_fused(
    const float* __restrict__ p0, const float* __restrict__ p1, const float* __restrict__ p2,
    const float* __restrict__ gt_bboxes, const int* __restrict__ gt_labels,
    const int* __restrict__ matched, double* __restrict__ acc)
{
    const int a = blockIdx.x * blockDim.x + threadIdx.x;
    const int b = blockIdx.y;
    const int slot = blockIdx.x & (NSLOT - 1);
    float cls_acc = 0.f, iou_acc = 0.f, dfl_acc = 0.f, pos_cnt = 0.f;
    if (a < NA) {
        const float* p; int HW, W; float stride; int off;
        if (a < 6400)      { p = p0; HW = 6400; W = 80; stride = 8.f;  off = a; }
        else if (a < 8000) { p = p1; HW = 1600; W = 40; stride = 16.f; off = a - 6400; }
        else               { p = p2; HW = 400;  W = 20; stride = 32.f; off = a - 8000; }
        const int h = off / W, w = off - h * W;
        const float cx = ((float)w + 0.5f) * stride, cy = ((float)h + 0.5f) * stride;
        const float* pb = p + ((size_t)b * 144) * (size_t)HW + (size_t)off;
        const int m = matched[(size_t)b * NA + a];
        const bool pos = (m >= 0);
        const int idx = pos ? m : 0;
        const int lbl = gt_labels[b * MAX_GT + idx];
        const float* tbp = gt_bboxes + ((size_t)b * MAX_GT + idx) * 4;
        const float tx1 = tbp[0], ty1 = tbp[1], tx2 = tbp[2], ty2 = tbp[3];
        float tdist[4] = {fmaxf(cx - tx1, 0.f) / stride, fmaxf(cy - ty1, 0.f) / stride,
                          fmaxf(tx2 - cx, 0.f) / stride, fmaxf(ty2 - cy, 0.f) / stride};
        float pdv[4]; float dfl_sum = 0.f;
        #pragma unroll
        for (int k = 0; k < 4; ++k) {
            float tv = fminf(tdist[k], (float)(BINS - 1) - 1e-6f);
            int lo = (int)floorf(tv);
            float fr = tv - (float)lo;
            const float* pc = pb + (size_t)(k * BINS) * HW;
            float v[BINS];
            #pragma unroll
            for (int i = 0; i < BINS; ++i) v[i] = pc[(size_t)i * HW];
            float mx = v[0];
            #pragma unroll
            for (int i = 1; i < BINS; ++i) mx = fmaxf(mx, v[i]);
            float se = 0.f, we = 0.f, vlo = 0.f, vhi = 0.f;
            #pragma unroll
            for (int i = 0; i < BINS; ++i) {
                float e = __expf(v[i] - mx);
                se += e; we += (float)i * e;
                vlo = (i == lo) ? v[i] : vlo;
                vhi = (i == lo + 1) ? v[i] : vhi;
            }
            pdv[k] = (we / se) * stride;
            if (pos) { float lse = mx + __logf(se); dfl_sum += -((1.f - fr) * (vlo - lse) + fr * (vhi - lse)); }
        }
        const float* pcls = pb + (size_t)(4 * BINS) * HW;
        #pragma unroll 4
        for (int c = 0; c < NCLS; ++c)
            cls_acc += focal_elem(pcls[(size_t)c * HW], (pos && c == lbl) ? 1.f : 0.f);
        if (pos) {
            float px1 = cx - pdv[0], py1 = cy - pdv[1], px2 = cx + pdv[2], py2 = cy + pdv[3];
            float ix1 = fmaxf(px1, tx1), iy1 = fmaxf(py1, ty1);
            float ix2 = fminf(px2, tx2), iy2 = fminf(py2, ty2);
            float inter  = fmaxf(ix2 - ix1, 0.f) * fmaxf(iy2 - iy1, 0.f);
            float area_p = fmaxf(px2 - px1, 0.f) * fmaxf(py2 - py1, 0.f);
            float area_t = fmaxf(tx2 - tx1, 0.f) * fmaxf(ty2 - ty1, 0.f);
            float iou = inter / (area_p + area_t - inter + EPS_F);
            iou_acc = 1.f - iou; dfl_acc = dfl_sum; pos_cnt = 1.f;
        }
    }
    block_reduce_atomic(cls_acc, &acc[0 * NSLOT + slot]);
    block_reduce_atomic(iou_acc, &acc[1 * NSLOT + slot]);
    block_reduce_atomic(dfl_acc, &acc[2 * NSLOT + slot]);
    block_reduce_atomic(pos_cnt, &acc[3 * NSLOT + slot]);
}

__global__ void yolo_loss_finalize(const double* __restrict__ acc, float* __restrict__ out)
{
    double s[4] = {0.0, 0.0, 0.0, 0.0};
    for (int q = 0; q < 4; ++q)
        for (int i = 0; i < NSLOT; ++i) s[q] += acc[q * NSLOT + i];
    double np = s[3] < 1.0 ? 1.0 : s[3];
    double total = W_CLS * s[0] / np + W_IOU * s[1] / np + W_DFL * s[2] / (np * 4.0);
    out[0] = (float)total;
}

extern "C" void kernel_launch(void* const* d_in, const int* in_sizes, int n_in,
                              void* d_out, int out_size, void* d_ws, size_t ws_size,
                              hipStream_t stream)
{
    const float* p0        = (const float*)d_in[0];
    const float* p1        = (const float*)d_in[1];
    const float* p2        = (const float*)d_in[2];
    const float* gt_bboxes = (const float*)d_in[3];
    const int*   gt_labels = (const int*)d_in[4];
    const int*   matched   = (const int*)d_in[5];
    float*  out = (float*)d_out;

    const size_t accBytes = 4 * NSLOT * sizeof(double);                 // 2048
    double*      acc    = (double*)d_ws;
    signed char* lblmap = (signed char*)((char*)d_ws + accBytes);
    const size_t need = accBytes + (size_t)AN;                          // ~271 KB

    if (ws_size >= need) {
        yolo_prep<<<(AN / 4 + 255) / 256, 256, 0, stream>>>(matched, gt_labels, lblmap, acc);
        yolo_mega<<<NB_DFL + NB_CLS, 256, 0, stream>>>(p0, p1, p2, gt_bboxes, matched,
                                                       lblmap, acc);
    } else {
        (void)hipMemsetAsync(acc, 0, accBytes, stream);
        dim3 g((NA + 255) / 256, BATCH);
        yolo_loss_fused<<<g, 256, 0, stream>>>(p0, p1, p2, gt_bboxes, gt_labels, matched, acc);
    }
    yolo_loss_finalize<<<1, 1, 0, stream>>>(acc, out);
}